// Round 3
// baseline (821.977 us; speedup 1.0000x reference)
//
#include <hip/hip_runtime.h>

// LIF constants (fp32 renderings of the reference's Python floats)
// tau_m = R*C = 150.00000000000003 -> fp32(tm) = 150.0f exactly.
#define DT_F    0.01f
#define TM_F    150.0f
#define R_F     3000.0f
#define V_THR_F 15.0f
#define V_MAX_F 30.0f

// EXPERIMENT NOTE (round 3): this is byte-for-byte the round-1 kernel.
// Round 1 PASSED the pre-timing correctness check (absmax 0.0625 = the
// harness's bf16 comparison floor at |v|<=30, i.e. every spike decision
// matched the np fp32 reference) and failed only the post-timing recheck
// with absmax exactly 30.0, reproduced identically by 5 fresh launches.
// A deterministic kernel on pristine-restored inputs must reproduce its
// pre-check output, so that failure is not explainable by this code; we
// re-run it to test reproducibility. Round 2's intrinsic-based variant
// produced a stub-identical failure (output ~zeros) and is abandoned.
//
// Numerics: plain ops in the EXACT reference op order
//     v + ((-v + R*i) / tm) * dt
// with fp contraction disabled -- a single FMA can flip a spike at the
// v>=15 threshold and blow absmax to 30.
template <int U>
__global__ __launch_bounds__(256) void lif_kernel(const float* __restrict__ stim,
                                                  float* __restrict__ out,
                                                  int T, int N) {
#pragma clang fp contract(off)
    const int n = blockIdx.x * blockDim.x + threadIdx.x;
    if (n >= N) return;

    const float* sp = stim + n;
    float*       op = out + n;

    float v = 0.0f;
    int t = 0;
    for (; t + U <= T; t += U) {
        float s[U];
#pragma unroll
        for (int u = 0; u < U; ++u) {
            s[u] = sp[(size_t)(t + u) * (size_t)N];   // U independent loads in flight
        }
#pragma unroll
        for (int u = 0; u < U; ++u) {
            // step 1: reset-from-spike OR Euler step (exact ref op order)
            float v_euler = v + ((-v + R_F * s[u]) / TM_F) * DT_F;
            float vn = (v >= V_THR_F) ? 0.0f : v_euler;
            // step 2: spike clamp
            vn = (vn >= V_THR_F) ? V_MAX_F : vn;
            v = vn;
            op[(size_t)(t + u) * (size_t)N] = v;
        }
    }
    for (; t < T; ++t) {
        float s = sp[(size_t)t * (size_t)N];
        float v_euler = v + ((-v + R_F * s) / TM_F) * DT_F;
        float vn = (v >= V_THR_F) ? 0.0f : v_euler;
        vn = (vn >= V_THR_F) ? V_MAX_F : vn;
        v = vn;
        op[(size_t)t * (size_t)N] = v;
    }
}

extern "C" void kernel_launch(void* const* d_in, const int* in_sizes, int n_in,
                              void* d_out, int out_size, void* d_ws, size_t ws_size,
                              hipStream_t stream) {
    const float* stim = (const float*)d_in[0];
    float*       out  = (float*)d_out;

    constexpr int T = 1000;
    constexpr int N = 131072;   // in_sizes[0] == T*N == 131072000

    constexpr int BLOCK = 256;
    const int grid = (N + BLOCK - 1) / BLOCK;   // 512 blocks -> 2 blocks/CU
    lif_kernel<8><<<grid, BLOCK, 0, stream>>>(stim, out, T, N);
}